// Round 1
// 161.869 us; speedup vs baseline: 1.0105x; 1.0105x over previous
//
#include <hip/hip_runtime.h>

namespace {
constexpr int CC    = 10;                  // cluster gap window C
constexpr int TT    = 500;                 // time steps
constexpr int NN    = 128;                 // neurons per batch row
constexpr int G     = 10;                  // t-segments per trace
constexpr int LSEG  = TT / G;              // 50 core steps
constexpr int HALO  = CC;                  // 10
constexpr int NSLOT = 10;                  // ws record: 5 cluster maxes + 5 scalars
constexpr int MAXG  = TT / (CC + 1) + 1;   // 46 max global clusters
constexpr int NELEM = LSEG + 2 * HALO;     // 70 column values per thread
}

// ---------------- kernel A: per-segment scan, ALL loads preloaded to registers ----------------
// sched_barrier(0) pins the 70 loads above the scan: maximal MLP, one latency exposure.
__global__ __launch_bounds__(128, 4)
void seg_scan_kernel(const float* __restrict__ vmem, float* __restrict__ ws,
                     float* __restrict__ out) {
    const int s   = blockIdx.x;            // segment 0..9
    const int b   = blockIdx.y;
    const int tid = threadIdx.x;           // neuron 0..127
    const int a   = s * LSEG;
    const float* __restrict__ col = vmem + b * TT * NN + tid;   // int math: fits 2^31 bytes

    if (s == 0 && b == 0 && tid == 0) out[0] = 0.0f;   // folded memset (merge runs after)

    __shared__ float stg[5 * NN];          // 2.5 KB: cluster-max staging only

    // ---- preload all 70 values (i covers ofs = i-10 in [-10, 60)) ----
    float r[NELEM];
    #pragma unroll
    for (int i = 0; i < NELEM; ++i) {
        int t = a + i - HALO;
        t = t < 0 ? 0 : (t > TT - 1 ? TT - 1 : t);     // clamp; masked in scan
        r[i] = col[t * NN];
    }
    __builtin_amdgcn_sched_barrier(0);     // loads may NOT sink into the scan

    int   ls = -(1 << 20), lcount = 0, hdne = 0, tmn = 0, hasu = 0;
    float ccm = -1e30f, rmax = -1e30f, hdm = -1e30f, vmx = -1e30f, m0 = -1e30f;
    const bool firstSeg = (s == 0), lastSeg = (s == G - 1);
    #pragma unroll
    for (int i = 0; i < 5; ++i) stg[i * NN + tid] = 0.0f;

    #pragma unroll
    for (int i = 0; i < NELEM; ++i) {
        const int ofs = i - HALO;                      // compile-time
        const int t   = a + ofs;
        float v = r[i];
        if ((ofs < 0 && firstSeg) || (ofs >= LSEG && lastSeg)) v = -1.0f;
        const bool spike = v >= 0.0f;
        if (ofs >= 0 && ofs < LSEG) {                  // core accounting
            const float rm2 = fmaxf(rmax, v);
            if (spike) {
                if (t - ls > CC) {                     // halo gives full C history
                    if (lcount > 0) stg[(lcount - 1) * NN + tid] = ccm;
                    ccm = v; ++lcount;
                } else if (lcount == 0) { hdne = 1; hdm = fmaxf(hdm, rm2); }
                else ccm = fmaxf(ccm, rm2);
                rmax = -1e30f;
            } else rmax = rm2;
            if (v > vmx) { vmx = v; tmn = t; }         // strict >: first argmax
        }
        if (spike) ls = t;                             // halo spikes count for ls
        if (ofs >= HALO) {                             // eval u = t-10 in [a, a+50)
            const float vu = r[i - 10];                // raw v[t-10]
            if (ls < t - 2 * CC) { hasu = 1; if (vu > m0) m0 = vu; }
        }
    }
    if (lcount > 0) stg[(lcount - 1) * NN + tid] = ccm;   // close final cluster

    // coalesced output: 10 rows of 512 B
    float* __restrict__ wsl = ws + (size_t)(b * G + s) * NSLOT * NN + tid;
    #pragma unroll
    for (int i = 0; i < 5; ++i) wsl[i * NN] = stg[i * NN + tid];
    const int packed = lcount | (hdne << 3) | (hasu << 4) | (tmn << 5);
    wsl[5 * NN] = __int_as_float(packed);
    wsl[6 * NN] = hdm;     // head-piece max
    wsl[7 * NN] = rmax;    // tail gap max (since last core spike)
    wsl[8 * NN] = vmx;
    wsl[9 * NN] = m0;
}

// ---------------- kernel B: merge segments + loss (256 thr = 2 batches/block) ----------------
__global__ __launch_bounds__(256, 1)
void merge_kernel(const float* __restrict__ vmem, const float* __restrict__ ws,
                  const int* __restrict__ labels, float* __restrict__ out) {
    const int tid  = threadIdx.x;          // 0..255
    const int lane = tid & 63;
    const int wv   = tid >> 6;             // wave 0..3
    const int b    = blockIdx.x * 2 + (tid >> 7);
    const int n    = tid & 127;

    __shared__ float gl[MAXG * 256];       // 47 KB compact global cluster lists
    __shared__ float wb[4][512];           // per-wave pass-2 column staging
    __shared__ float red[4];

    // ---- preload all 100 ws values to registers (occupancy is grid-limited; VGPRs free) ----
    const float* __restrict__ wsb = ws + (size_t)b * G * NSLOT * NN + n;
    float f[G * NSLOT];
    #pragma unroll
    for (int k = 0; k < G * NSLOT; ++k) f[k] = wsb[(size_t)k * NN];
    __builtin_amdgcn_sched_barrier(0);

    const int label = labels[b * NN + n];

    int g = 0, g_nc = 0, g_hasu = 0, g_tm = 0;
    bool open = false; float cur = -1e30f, ptg = -1e30f;
    float g_vmax = -1e30f, g_m0 = -1e30f;
    #pragma unroll
    for (int s2 = 0; s2 < G; ++s2) {
        const float* d = &f[s2 * NSLOT];
        const int pk = __float_as_int(d[5]);
        const int k = pk & 7, hne = (pk >> 3) & 1;
        g_nc += k; g_hasu |= (pk >> 4) & 1;
        if (d[8] > g_vmax) { g_vmax = d[8]; g_tm = pk >> 5; }
        if (d[9] > g_m0) g_m0 = d[9];
        if (open) {
            if (hne) { cur = fmaxf(cur, fmaxf(ptg, d[6])); ptg = d[7]; }
            if (k > 0 || !hne) { gl[g * 256 + tid] = cur; ++g; open = false; }
        }
        if (k > 0) {
            #pragma unroll
            for (int i = 0; i < 4; ++i)
                if (i < k - 1) { gl[g * 256 + tid] = d[i]; ++g; }
            float last = d[4];                 // select d[k-1]
            if (k == 1) last = d[0];
            else if (k == 2) last = d[1];
            else if (k == 3) last = d[2];
            else if (k == 4) last = d[3];
            cur = last; open = true; ptg = d[7];
        }
    }
    if (open) { gl[g * 256 + tid] = cur; ++g; }        // g == g_nc

    // pass-2 m_rest: wave-cooperative, rare (needs a 21-step spike-free window)
    const bool need2 = (label > g_nc) && g_hasu && (label - g_nc >= 2);
    float mrest = g_vmax;                              // full2 surrogate default
    unsigned long long bal = __ballot(need2);          // wave-uniform
    const float* colbase = vmem + (size_t)b * TT * NN;
    float* __restrict__ wbp = wb[wv];
    while (bal) {
        const int fl = __ffsll((unsigned long long)bal) - 1;
        bal &= bal - 1;
        const int   nf    = ((wv & 1) << 6) | fl;      // flagged neuron (wave's n-range)
        const int   tmf   = __shfl(g_tm, fl);
        const float vmaxf = __shfl(g_vmax, fl);
        #pragma unroll
        for (int j = 0; j < 8; ++j) {                  // stage column: 8 loads/lane
            const int t = lane * 8 + j;
            wbp[t] = (t < TT) ? colbase[(size_t)t * NN + nf] : -1.0f;
        }
        asm volatile("s_waitcnt lgkmcnt(0)" ::: "memory");  // wave-lockstep LDS visibility
        __builtin_amdgcn_wave_barrier();
        int ls2 = -1000, lh = 0; float lm = -1e30f;
        const int u0 = lane * 8;
        for (int t2 = u0 - 10; t2 < u0 + 18; ++t2) {
            const float v = (t2 >= 0 && t2 < 512) ? wbp[t2] : -1.0f;
            if (v >= 0.0f) ls2 = t2;
            const int u = t2 - 10;
            if (u >= u0 && u < u0 + 8 && u < TT) {
                if (ls2 < u - 10 && (u < tmf - CC / 2 || u > tmf + CC / 2)) {
                    lh = 1; const float vu = wbp[u]; if (vu > lm) lm = vu;
                }
            }
        }
        #pragma unroll
        for (int off = 32; off > 0; off >>= 1) {       // wave reduce
            lm = fmaxf(lm, __shfl_down(lm, off));
            lh |= __shfl_down(lh, off);
        }
        const float res = __shfl(lh ? lm : vmaxf, 0);
        if (lane == fl) mrest = res;
        __builtin_amdgcn_wave_barrier();
    }

    // branch select
    float contrib = 0.0f;
    if (label > g_nc) {
        if (!g_hasu) contrib = g_vmax;                 // full0 -> vmax
        else {
            const float dE = (float)(label - g_nc);    // >= 1
            contrib = -((g_m0 + (dE - 1.0f) * mrest) / dE);
        }
    } else if (label < g_nc) {
        const int kk = g_nc - label;                   // 1..nc
        float ssum = 0.0f;
        for (int i = 0; i < kk; ++i) {                 // sum kk smallest cluster maxes
            float mn = 1e30f; int mj = 0;
            for (int jj = 0; jj < g_nc; ++jj) {
                const float x = gl[jj * 256 + tid];
                if (x < mn) { mn = x; mj = jj; }
            }
            ssum += mn; gl[mj * 256 + tid] = 1e30f;
        }
        contrib = ssum / (float)kk;
    }

    out[1 + b * NN + n] = (float)g_nc;                 // spike_output

    // block reduce: wave shuffle -> LDS -> single atomic per block (128 total)
    float w = contrib;
    #pragma unroll
    for (int off = 32; off > 0; off >>= 1) w += __shfl_down(w, off);
    if (lane == 0) red[wv] = w;
    __syncthreads();
    if (tid == 0) atomicAdd(out, red[0] + red[1] + red[2] + red[3]);
}

extern "C" void kernel_launch(void* const* d_in, const int* in_sizes, int n_in,
                              void* d_out, int out_size, void* d_ws, size_t ws_size,
                              hipStream_t stream) {
    const float* vmem   = (const float*)d_in[0];
    // d_in[1] (vlastmem) and d_in[3] (ratio) are unused by the reference forward.
    const int*   labels = (const int*)d_in[2];
    float*       out    = (float*)d_out;
    float*       ws     = (float*)d_ws;   // 256*10*10*128*4 = 13.1 MB

    const int B = in_sizes[2] / NN;       // 256

    hipLaunchKernelGGL(seg_scan_kernel, dim3(G, B), dim3(NN), 0, stream, vmem, ws, out);
    hipLaunchKernelGGL(merge_kernel, dim3(B / 2), dim3(256), 0, stream, vmem, ws, labels, out);
}

// Round 2
// 159.527 us; speedup vs baseline: 1.0253x; 1.0147x over previous
//
#include <hip/hip_runtime.h>

namespace {
constexpr int CC    = 10;                  // cluster gap window C
constexpr int TT    = 500;                 // time steps
constexpr int NN    = 128;                 // neurons per batch row
constexpr int NG    = 4;                   // temporal groups per block
constexpr int LSEG  = TT / NG;             // 125 core steps per group
constexpr int HALO  = CC;                  // 10
constexpr int NCH   = 15;                  // chunks of 10 covering ofs in [-10, 140)
constexpr int MAXK  = 12;                  // max clusters in a 125-step segment
constexpr int MAXG  = TT / (CC + 1) + 1;   // 46 max global clusters
}

// ---------------- single fused kernel: 4 in-block temporal segments + merge + loss --------
// No workspace at all: segment records pass through LDS; one block per batch.
__global__ __launch_bounds__(512, 2)
void fused_kernel(const float* __restrict__ vmem, const int* __restrict__ labels,
                  float* __restrict__ out) {
    const int tid = threadIdx.x;           // 0..511
    const int g   = tid >> 7;              // temporal group 0..3
    const int n   = tid & 127;             // neuron
    const int b   = blockIdx.x;            // batch
    const int a   = g * LSEG;
    const bool firstSeg = (g == 0), lastSeg = (g == NG - 1);
    const float* __restrict__ col = vmem + (size_t)b * TT * NN + n;

    __shared__ float s_cl[NG][MAXK][NN];   // 24.6 KB per-segment cluster maxes
    __shared__ int   s_pk[NG][NN];         // packed: lcount | hdne<<4 | hasu<<5 | tmn<<6
    __shared__ float s_hdm[NG][NN], s_tg[NG][NN], s_vm[NG][NN], s_m0[NG][NN];
    __shared__ float s_gl[MAXG][NN];       // 23.5 KB global cluster list (merge phase)
    __shared__ float wb[2][512];           // per-wave pass-2 column staging
    __shared__ float red[2];

    // ---- rolling 4-buffer chunk pipeline (chunk c covers ofs = -10+10c .. -1+10c) ----
    float b0[10], b1[10], b2[10], b3[10] = {};

    auto load = [&](float (&d)[10], int c) {
        if ((firstSeg && c == 0) || (lastSeg && c >= 13)) {   // only edges need clamping
            #pragma unroll
            for (int j = 0; j < 10; ++j) {
                int t = a - HALO + 10 * c + j;
                t = t < 0 ? 0 : (t > TT - 1 ? TT - 1 : t);    // clamp; masked in scan
                d[j] = col[t * NN];
            }
        } else {                                              // affine: base + imm offsets
            const float* __restrict__ p = col + (a - HALO + 10 * c) * NN;
            #pragma unroll
            for (int j = 0; j < 10; ++j) d[j] = p[j * NN];
        }
    };

    int   ls = -(1 << 20), lcount = 0, hdne = 0, tmn = 0, hasu = 0;
    float ccm = -1e30f, rmax = -1e30f, hdm = -1e30f, vmx = -1e30f, m0 = -1e30f;

    auto scan = [&](const float (&cur)[10], const float (&prev)[10], int c) {
        #pragma unroll
        for (int j = 0; j < 10; ++j) {
            const int ofs = -HALO + 10 * c + j;               // compile-time after inline
            const int t   = a + ofs;
            float v = cur[j];
            if ((ofs < 0 && firstSeg) || (ofs >= LSEG && lastSeg)) v = -1.0f;
            const bool spike = v >= 0.0f;
            if (ofs >= 0 && ofs < LSEG) {                     // core accounting
                const float rm2 = fmaxf(rmax, v);
                if (spike) {
                    if (t - ls > CC) {                        // halo gives full C history
                        if (lcount > 0) s_cl[g][lcount - 1][n] = ccm;
                        ccm = v; ++lcount;
                    } else if (lcount == 0) { hdne = 1; hdm = fmaxf(hdm, rm2); }
                    else ccm = fmaxf(ccm, rm2);
                    rmax = -1e30f;
                } else rmax = rm2;
                if (v > vmx) { vmx = v; tmn = t; }            // strict >: first argmax
            }
            if (spike) ls = t;                                // halo/tail spikes feed ls
            if (ofs >= HALO && ofs < LSEG + HALO) {           // eval u = t-10 in core
                const float vu = prev[j];                     // raw v[t-10]
                if (ls < t - 2 * CC) { hasu = 1; if (vu > m0) m0 = vu; }
            }
        }
    };

    #define SB __builtin_amdgcn_sched_barrier(0)
    load(b0, 0);  load(b1, 1);  SB;
    load(b2, 2);  SB; scan(b0, b3, 0);  SB;   // prev unused at c=0 (ofs<10 compile-time)
    load(b3, 3);  SB; scan(b1, b0, 1);  SB;
    load(b0, 4);  SB; scan(b2, b1, 2);  SB;
    load(b1, 5);  SB; scan(b3, b2, 3);  SB;
    load(b2, 6);  SB; scan(b0, b3, 4);  SB;
    load(b3, 7);  SB; scan(b1, b0, 5);  SB;
    load(b0, 8);  SB; scan(b2, b1, 6);  SB;
    load(b1, 9);  SB; scan(b3, b2, 7);  SB;
    load(b2, 10); SB; scan(b0, b3, 8);  SB;
    load(b3, 11); SB; scan(b1, b0, 9);  SB;
    load(b0, 12); SB; scan(b2, b1, 10); SB;
    load(b1, 13); SB; scan(b3, b2, 11); SB;
    load(b2, 14); SB; scan(b0, b3, 12); SB;
    scan(b1, b0, 13); scan(b2, b1, 14);
    #undef SB

    if (lcount > 0) s_cl[g][lcount - 1][n] = ccm;   // close final cluster

    s_pk[g][n]  = lcount | (hdne << 4) | (hasu << 5) | (tmn << 6);
    s_hdm[g][n] = hdm;     // head-piece max
    s_tg[g][n]  = rmax;    // tail gap max (since last core spike)
    s_vm[g][n]  = vmx;
    s_m0[g][n]  = m0;
    __syncthreads();

    // ---------------- merge + loss: group 0 only (one thread per neuron) ----------------
    if (tid < NN) {
        const int lane = tid & 63, wv = tid >> 6;
        int gi = 0, g_nc = 0, g_hasu = 0, g_tm = 0;
        bool open = false; float cur = -1e30f, ptg = -1e30f;
        float g_vmax = -1e30f, g_m0 = -1e30f;
        #pragma unroll
        for (int s = 0; s < NG; ++s) {
            const int pk = s_pk[s][tid];
            const int k = pk & 15, hne = (pk >> 4) & 1;
            g_nc += k; g_hasu |= (pk >> 5) & 1;
            const float vmS = s_vm[s][tid];
            if (vmS > g_vmax) { g_vmax = vmS; g_tm = pk >> 6; }   // segment order = t order
            const float m0S = s_m0[s][tid];
            if (m0S > g_m0) g_m0 = m0S;
            if (open) {
                if (hne) { cur = fmaxf(cur, fmaxf(ptg, s_hdm[s][tid])); ptg = s_tg[s][tid]; }
                if (k > 0 || !hne) { s_gl[gi][tid] = cur; ++gi; open = false; }
            }
            if (k > 0) {
                for (int i = 0; i < k - 1; ++i) { s_gl[gi][tid] = s_cl[s][i][tid]; ++gi; }
                cur = s_cl[s][k - 1][tid]; open = true; ptg = s_tg[s][tid];
            }
        }
        if (open) { s_gl[gi][tid] = cur; ++gi; }       // gi == g_nc

        const int label = labels[b * NN + tid];

        // pass-2 m_rest: wave-cooperative, rare (needs a 21-step spike-free window)
        const bool need2 = (label > g_nc) && g_hasu && (label - g_nc >= 2);
        float mrest = g_vmax;                          // full2 surrogate default
        unsigned long long bal = __ballot(need2);      // waves 0/1 fully inside tid<128
        const float* colbase = vmem + (size_t)b * TT * NN;
        float* __restrict__ wbp = wb[wv];
        while (bal) {
            const int fl = __ffsll((unsigned long long)bal) - 1;
            bal &= bal - 1;
            const int   nf    = (wv << 6) | fl;        // flagged neuron (wave's n-range)
            const int   tmf   = __shfl(g_tm, fl);
            const float vmaxf = __shfl(g_vmax, fl);
            #pragma unroll
            for (int j = 0; j < 8; ++j) {              // stage column: 8 loads/lane
                const int t = lane * 8 + j;
                wbp[t] = (t < TT) ? colbase[(size_t)t * NN + nf] : -1.0f;
            }
            asm volatile("s_waitcnt lgkmcnt(0)" ::: "memory");  // wave-lockstep LDS
            __builtin_amdgcn_wave_barrier();
            int ls2 = -1000, lh = 0; float lm = -1e30f;
            const int u0 = lane * 8;
            for (int t2 = u0 - 10; t2 < u0 + 18; ++t2) {
                const float v = (t2 >= 0 && t2 < 512) ? wbp[t2] : -1.0f;
                if (v >= 0.0f) ls2 = t2;
                const int u = t2 - 10;
                if (u >= u0 && u < u0 + 8 && u < TT) {
                    if (ls2 < u - 10 && (u < tmf - CC / 2 || u > tmf + CC / 2)) {
                        lh = 1; const float vu = wbp[u]; if (vu > lm) lm = vu;
                    }
                }
            }
            #pragma unroll
            for (int off = 32; off > 0; off >>= 1) {   // wave reduce
                lm = fmaxf(lm, __shfl_down(lm, off));
                lh |= __shfl_down(lh, off);
            }
            const float res = __shfl(lh ? lm : vmaxf, 0);
            if (lane == fl) mrest = res;
            __builtin_amdgcn_wave_barrier();
        }

        // branch select
        float contrib = 0.0f;
        if (label > g_nc) {
            if (!g_hasu) contrib = g_vmax;             // full0 -> vmax
            else {
                const float dE = (float)(label - g_nc);        // >= 1
                contrib = -((g_m0 + (dE - 1.0f) * mrest) / dE);
            }
        } else if (label < g_nc) {
            const int kk = g_nc - label;               // 1..nc
            float ssum = 0.0f;
            for (int i = 0; i < kk; ++i) {             // sum kk smallest cluster maxes
                float mn = 1e30f; int mj = 0;
                for (int jj = 0; jj < g_nc; ++jj) {
                    const float x = s_gl[jj][tid];
                    if (x < mn) { mn = x; mj = jj; }
                }
                ssum += mn; s_gl[mj][tid] = 1e30f;
            }
            contrib = ssum / (float)kk;
        }

        out[1 + b * NN + tid] = (float)g_nc;           // spike_output

        float w = contrib;                             // 2-wave block reduce
        #pragma unroll
        for (int off = 32; off > 0; off >>= 1) w += __shfl_down(w, off);
        if (lane == 0) red[wv] = w;
    }
    __syncthreads();
    if (tid == 0) atomicAdd(out, red[0] + red[1]);     // 1 atomic per batch (256 total)
}

extern "C" void kernel_launch(void* const* d_in, const int* in_sizes, int n_in,
                              void* d_out, int out_size, void* d_ws, size_t ws_size,
                              hipStream_t stream) {
    const float* vmem   = (const float*)d_in[0];
    // d_in[1] (vlastmem) and d_in[3] (ratio) are unused by the reference forward.
    const int*   labels = (const int*)d_in[2];
    float*       out    = (float*)d_out;
    (void)d_ws; (void)ws_size;                         // workspace deliberately untouched

    const int B = in_sizes[2] / NN;                    // 256

    hipMemsetAsync(out, 0, sizeof(float), stream);     // zero the loss accumulator
    hipLaunchKernelGGL(fused_kernel, dim3(B), dim3(512), 0, stream, vmem, labels, out);
}